// Round 12
// baseline (571.225 us; speedup 1.0000x reference)
//
#include <hip/hip_runtime.h>
#include <math.h>
#include <float.h>

#define EPSV 1e-8f
constexpr int D = 64;

typedef __attribute__((ext_vector_type(8)))  short short8;
typedef __attribute__((ext_vector_type(16))) float f32x16;

static __device__ __forceinline__ unsigned short f2bf(float f) {
    unsigned u = __float_as_uint(f);
    unsigned r = u + 0x7FFFu + ((u >> 16) & 1u);   // round-to-nearest-even
    return (unsigned short)(r >> 16);
}
static __device__ __forceinline__ float bf2f(unsigned short b) {
    return __uint_as_float(((unsigned)b) << 16);
}
static __device__ __forceinline__ unsigned umin2(unsigned a, unsigned b) { return a < b ? a : b; }
static __device__ __forceinline__ unsigned umax2(unsigned a, unsigned b) { return a > b ? a : b; }

// fragment-ready layout: entity panel p=e>>5, k-slot q=k>>3:
//   u16 index = p*2048 + q*256 + (e&31)*8 + (k&7)
static __device__ __forceinline__ size_t fragidx(int e, int k) {
    return (size_t)(e >> 5) * 2048 + (size_t)(k >> 3) * 256 + (e & 31) * 8 + (k & 7);
}

// ---------------------------------------------------------------------------
// prep: normalize codebook. cb fp32 (for gather) + double-normalized hi/lo
// bf16 fragments.
// ---------------------------------------------------------------------------
__global__ __launch_bounds__(256) void k_prep_cb(const float* __restrict__ cbin,
                                                 float* __restrict__ cb,
                                                 unsigned short* __restrict__ ch,
                                                 unsigned short* __restrict__ cl) {
    const int t = threadIdx.x;
    const int wv = t >> 6, lane = t & 63;
    const int code = blockIdx.x * 4 + wv;
    float v = cbin[(size_t)code * D + lane];
    float ss = v * v;
    #pragma unroll
    for (int off = 32; off; off >>= 1) ss += __shfl_xor(ss, off, 64);
    const float c1 = v / (sqrtf(ss) + EPSV);
    cb[(size_t)code * D + lane] = c1;
    float ss2 = c1 * c1;
    #pragma unroll
    for (int off = 32; off; off >>= 1) ss2 += __shfl_xor(ss2, off, 64);
    const float c2 = c1 / (sqrtf(ss2) + EPSV);
    const unsigned short h = f2bf(c2);
    const size_t fi = fragidx(code, lane);
    ch[fi] = h;
    cl[fi] = f2bf(c2 - bf2f(h));
}

// ---------------------------------------------------------------------------
// prep: normalize x -> xn (fp32, straight to d_out region 2) + hi/lo fragments
// also zeroes fixcnt (stream-ordered before k_reduce2)
// ---------------------------------------------------------------------------
__global__ __launch_bounds__(256) void k_prep_x(const float* __restrict__ xin,
                                                float* __restrict__ xn,
                                                unsigned short* __restrict__ xh,
                                                unsigned short* __restrict__ xl,
                                                int* __restrict__ fixcnt) {
    const int t = threadIdx.x;
    if (blockIdx.x == 0 && t == 0) *fixcnt = 0;
    const int wv = t >> 6, lane = t & 63;
    const int row = blockIdx.x * 4 + wv;
    float v = xin[(size_t)row * D + lane];
    float ss = v * v;
    #pragma unroll
    for (int off = 32; off; off >>= 1) ss += __shfl_xor(ss, off, 64);
    const float xv = v / (sqrtf(ss) + EPSV);
    xn[(size_t)row * D + lane] = xv;
    const unsigned short h = f2bf(xv);
    const size_t fi = fragidx(row, lane);
    xh[fi] = h;
    xl[fi] = f2bf(xv - bf2f(h));
}

// ---------------------------------------------------------------------------
// main: 128 rows x 2048 codes per block (32 tiles of 64 codes), 4 waves.
// Swapped MFMA (A=codes, B=x-rows): acc col = x-row -> lane-local argmin.
// BARRIER-FREE pipeline: mask slices are per-wave private, so tile sync is
// a per-wave counted s_waitcnt vmcnt(24) (24 = 8 stage + 16 frag newer ops)
// + sched_barrier(0). Next tile's code fragments prefetch into registers
// during current compute. No __syncthreads in the main loop.
// ---------------------------------------------------------------------------
__global__ __launch_bounds__(256, 2) void k_mfma(const unsigned short* __restrict__ xh,
                                                 const unsigned short* __restrict__ xl,
                                                 const unsigned short* __restrict__ ch,
                                                 const unsigned short* __restrict__ cl,
                                                 const int* __restrict__ mask,
                                                 const int* __restrict__ training,
                                                 unsigned* __restrict__ pk1,
                                                 unsigned* __restrict__ pk2,
                                                 int B, int K) {
    __shared__ int msk[2][4][32][64];            // 64 KB: [buf][wave][row][code]
    const int t = threadIdx.x;
    const int wv = t >> 6, lane = t & 63;
    const int lh = lane >> 5, lm = lane & 31;
    const int ks = (int)(blockIdx.x & 7);
    const int rb = (int)(blockIdx.x >> 3);
    const int tr = training[0];

    const short8* xh8 = (const short8*)xh;
    const short8* xl8 = (const short8*)xl;
    const short8* ch8 = (const short8*)ch;
    const short8* cl8 = (const short8*)cl;

    const int rp = rb * 4 + wv;                  // this wave's 32-row panel
    const int row = rp * 32 + lm;                // this lane's x-row
    const int lh4 = lh * 4;
    const int lsub = lane >> 4;                  // 0..3 (row within gll group)
    const int lquad = lane & 15;                 // 16B slot within row

    // B fragments (x rows), held for the whole block
    short8 bh[4], bl[4];
    #pragma unroll
    for (int s = 0; s < 4; ++s) {
        const size_t bi = (size_t)rp * 256 + (s * 2 + lh) * 32 + lm;
        bh[s] = xh8[bi];
        bl[s] = xl8[bi];
    }

    const int* mbase = mask + (size_t)(rp * 32) * K + ks * (K / 8);

    unsigned k1 = 0xFFFFFFFFu, k2 = 0xFFFFFFFFu;

    // stage tile tt_ into buffer b_: 8 x global_load_lds dwordx4 per wave.
    // source quad pre-swizzled (quad ^ (row&15)); reads undo with same XOR.
#define STAGE(b_, tt_) do {                                                    \
    _Pragma("unroll")                                                          \
    for (int j = 0; j < 8; ++j) {                                              \
        const int rj = j * 4 + lsub;                                           \
        const int qz = lquad ^ (rj & 15);                                      \
        const int* src = mbase + (size_t)rj * K + (tt_) * 64 + qz * 4;         \
        __builtin_amdgcn_global_load_lds(                                      \
            (const __attribute__((address_space(1))) void*)src,                \
            (__attribute__((address_space(3))) void*)(&msk[b_][wv][j * 4][0]), \
            16, 0, 0);                                                         \
    }                                                                          \
} while (0)

    // load both panels' code fragments of tile tt_ into named regs (16 x 16B)
#define FRAGLOAD(dh_, dl_, tt_) do {                                           \
    _Pragma("unroll")                                                          \
    for (int p = 0; p < 2; ++p) {                                              \
        const int cp = (ks * 32 + (tt_)) * 2 + p;                              \
        _Pragma("unroll")                                                      \
        for (int s = 0; s < 4; ++s) {                                          \
            const size_t ai = (size_t)cp * 256 + (s * 2 + lh) * 32 + lm;       \
            dh_[p * 4 + s] = ch8[ai];                                          \
            dl_[p * 4 + s] = cl8[ai];                                          \
        }                                                                      \
    }                                                                          \
} while (0)

    short8 ahc[8], alc[8], ahn[8], aln[8];
    STAGE(0, 0);
    FRAGLOAD(ahc, alc, 0);

    #pragma unroll 1
    for (int tt = 0; tt < 32; ++tt) {
        if (tt < 31) {
            STAGE((tt + 1) & 1, tt + 1);
            FRAGLOAD(ahn, aln, tt + 1);
            // stage(tt) is older than the 8+16 ops just issued -> done at <=24
            asm volatile("s_waitcnt vmcnt(24)" ::: "memory");
        } else {
            asm volatile("s_waitcnt vmcnt(0)" ::: "memory");
        }
        __builtin_amdgcn_sched_barrier(0);
        const int bsel = tt & 1;

        // build this lane's kept-bit word for its 32 codes of this tile
        unsigned kept = 0;
        #pragma unroll
        for (int i = 0; i < 8; ++i) {
            const int q = lh + 2 * i;            // quad of codes this lane uses
            const int4 v = *(const int4*)&msk[bsel][wv][lm][(q ^ (lm & 15)) * 4];
            kept |= (v.x != 0 ? 1u : 0u) << (i * 4 + 0);
            kept |= (v.y != 0 ? 1u : 0u) << (i * 4 + 1);
            kept |= (v.z != 0 ? 1u : 0u) << (i * 4 + 2);
            kept |= (v.w != 0 ? 1u : 0u) << (i * 4 + 3);
        }
        const unsigned nm = tr ? ~kept : 0u;     // bit=1 -> dropped code

        const int ct = ks * 32 + tt;             // global 64-code tile id
        #pragma unroll
        for (int p = 0; p < 2; ++p) {
            f32x16 acc;
            #pragma unroll
            for (int i = 0; i < 16; ++i) acc[i] = 0.f;
            #pragma unroll
            for (int s = 0; s < 4; ++s) {
                acc = __builtin_amdgcn_mfma_f32_32x32x16_bf16(ahc[p * 4 + s], bh[s], acc, 0, 0, 0);
                acc = __builtin_amdgcn_mfma_f32_32x32x16_bf16(ahc[p * 4 + s], bl[s], acc, 0, 0, 0);
                acc = __builtin_amdgcn_mfma_f32_32x32x16_bf16(alc[p * 4 + s], bh[s], acc, 0, 0, 0);
            }
            const unsigned kbase = (unsigned)(ct * 64 + p * 32 + lh4);
            #pragma unroll
            for (int r = 0; r < 16; ++r) {
                const int base = (r & 3) + 8 * (r >> 2);              // static
                const int bitpos = p * 16 + (r >> 2) * 4 + (r & 3);   // static
                const float qf = fmaf(acc[r], -65536.0f, 131072.0f);
                int qi = (int)qf;
                qi = qi < 0 ? 0 : (qi > 262143 ? 262143 : qi);
                unsigned key = ((unsigned)qi << 14) | kbase | (unsigned)base;
                key |= (unsigned)((int)(nm << (31 - bitpos)) >> 31);  // dropped
                k2 = umin2(k2, umax2(k1, key));
                k1 = umin2(k1, key);
            }
        }
        if (tt < 31) {
            #pragma unroll
            for (int i = 0; i < 8; ++i) { ahc[i] = ahn[i]; alc[i] = aln[i]; }
        }
    }
#undef FRAGLOAD
#undef STAGE

    // merge the two half-lanes holding the same x-row
    const unsigned o1 = (unsigned)__shfl_xor((int)k1, 32, 64);
    const unsigned o2 = (unsigned)__shfl_xor((int)k2, 32, 64);
    const unsigned mx = umax2(k1, o1);
    k1 = umin2(k1, o1);
    k2 = umin2(umin2(k2, o2), mx);

    if (lh == 0) {                               // coalesced 32-dword writes
        pk1[(size_t)ks * B + row] = k1;
        pk2[(size_t)ks * B + row] = k2;
    }
}

// ---------------------------------------------------------------------------
// combine the 8 ksplit partials per row; flag rows with top-2 gap < 10 quanta
// ---------------------------------------------------------------------------
__global__ __launch_bounds__(256) void k_reduce2(const unsigned* __restrict__ pk1,
                                                 const unsigned* __restrict__ pk2,
                                                 int* __restrict__ bestidx,
                                                 int* __restrict__ fixlist,
                                                 int* __restrict__ fixcnt,
                                                 int B) {
    const int row = blockIdx.x * 256 + threadIdx.x;
    unsigned k1 = 0xFFFFFFFFu, k2 = 0xFFFFFFFFu;
    #pragma unroll
    for (int c = 0; c < 8; ++c) {
        const unsigned a1 = pk1[(size_t)c * B + row];
        const unsigned a2 = pk2[(size_t)c * B + row];
        k2 = umin2(umin2(k2, a2), umax2(k1, a1));
        k1 = umin2(k1, a1);
    }
    bestidx[row] = (int)(k1 & 16383u);
    if ((k2 >> 14) - (k1 >> 14) < 10u) {
        const int p = atomicAdd(fixcnt, 1);
        fixlist[p] = row;
    }
}

// ---------------------------------------------------------------------------
// gather + write all outputs
// ---------------------------------------------------------------------------
__global__ __launch_bounds__(256) void k_out(const float* __restrict__ xn,
                                             const float* __restrict__ cb,
                                             const int* __restrict__ bestidx,
                                             float* __restrict__ out, int B) {
    const int t = threadIdx.x;
    const int wv = t >> 6, lane = t & 63;
    const int row = blockIdx.x * 4 + wv;
    const int bi = bestidx[row];
    const float zv  = cb[(size_t)bi * D + lane];
    const float xnv = xn[(size_t)row * D + lane];
    out[(size_t)row * D + lane] = xnv + (zv - xnv);                 // z_q
    out[(size_t)B * D + (size_t)row * D + lane] = zv;               // z
    if (lane == 0) out[(size_t)3 * B * D + row] = (float)bi;        // index
}

// ---------------------------------------------------------------------------
// exact fp32 rescan for flagged (near-tie) rows; overwrites their outputs
// ---------------------------------------------------------------------------
__global__ __launch_bounds__(256) void k_fix(const float* __restrict__ xn,
                                             const float* __restrict__ cb,
                                             const int* __restrict__ mask,
                                             const int* __restrict__ training,
                                             const int* __restrict__ fixlist,
                                             const int* __restrict__ fixcnt,
                                             float* __restrict__ out, int B, int K) {
    const int nf = *fixcnt;
    const int tr = training[0];
    __shared__ float sv[256];
    __shared__ int   si[256];
    const int t = threadIdx.x;
    for (int i = blockIdx.x; i < nf; i += gridDim.x) {
        const int row = fixlist[i];
        const float* xr = xn + (size_t)row * D;
        float b1 = FLT_MAX; int i1 = 0;
        for (int k = t; k < K; k += 256) {
            const float* cr = cb + (size_t)k * D;
            float s = 0.f;
            #pragma unroll
            for (int d = 0; d < D; ++d) s = fmaf(xr[d], cr[d], s);
            const int m = mask[(size_t)row * K + k];
            const float dist = (tr && m == 0) ? 1000000000.0f : -s;
            if (dist < b1) { b1 = dist; i1 = k; }
        }
        sv[t] = b1; si[t] = i1;
        __syncthreads();
        for (int s = 128; s; s >>= 1) {
            if (t < s) {
                const float ov = sv[t + s]; const int oi = si[t + s];
                if (ov < sv[t] || (ov == sv[t] && oi < si[t])) { sv[t] = ov; si[t] = oi; }
            }
            __syncthreads();
        }
        const int bi = si[0];
        if (t < 64) {
            const float zv  = cb[(size_t)bi * D + t];
            const float xnv = xr[t];
            out[(size_t)row * D + t] = xnv + (zv - xnv);
            out[(size_t)B * D + (size_t)row * D + t] = zv;
        }
        if (t == 0) out[(size_t)3 * B * D + row] = (float)bi;
        __syncthreads();
    }
}

extern "C" void kernel_launch(void* const* d_in, const int* in_sizes, int n_in,
                              void* d_out, int out_size, void* d_ws, size_t ws_size,
                              hipStream_t stream) {
    const float* x    = (const float*)d_in[0];
    const float* cbin = (const float*)d_in[1];
    const int* mask   = (const int*)d_in[2];
    const int* train  = (const int*)d_in[3];
    const int B = in_sizes[0] / D;   // 16384
    const int K = in_sizes[1] / D;   // 16384
    float* out = (float*)d_out;
    float* out_xn = out + (size_t)2 * B * D;

    char* w = (char*)d_ws;
    float* cbw          = (float*)w;                               // 4 MB
    unsigned short* xhw = (unsigned short*)(w + (size_t)K * D * 4);
    unsigned short* xlw = xhw + (size_t)B * D;
    unsigned short* chw = xlw + (size_t)B * D;
    unsigned short* clw = chw + (size_t)K * D;
    unsigned* pk1       = (unsigned*)(clw + (size_t)K * D);        // B*8 u32
    unsigned* pk2       = pk1 + (size_t)B * 8;                     // B*8 u32
    int* bestidx        = (int*)(pk2 + (size_t)B * 8);
    int* fixlist        = bestidx + B;
    int* fixcnt         = fixlist + B;

    k_prep_cb<<<K / 4, 256, 0, stream>>>(cbin, cbw, chw, clw);
    k_prep_x <<<B / 4, 256, 0, stream>>>(x, out_xn, xhw, xlw, fixcnt);
    k_mfma   <<<(B / 128) * 8, 256, 0, stream>>>(xhw, xlw, chw, clw, mask, train,
                                                 pk1, pk2, B, K);
    k_reduce2<<<B / 256, 256, 0, stream>>>(pk1, pk2, bestidx, fixlist, fixcnt, B);
    k_out    <<<B / 4, 256, 0, stream>>>(out_xn, cbw, bestidx, out, B);
    k_fix    <<<256, 256, 0, stream>>>(out_xn, cbw, mask, train, fixlist, fixcnt,
                                       out, B, K);
}

// Round 13
// 530.267 us; speedup vs baseline: 1.0772x; 1.0772x over previous
//
#include <hip/hip_runtime.h>
#include <math.h>
#include <float.h>

#define EPSV 1e-8f
constexpr int D = 64;

typedef __attribute__((ext_vector_type(8)))  short short8;
typedef __attribute__((ext_vector_type(16))) float f32x16;

static __device__ __forceinline__ unsigned short f2bf(float f) {
    unsigned u = __float_as_uint(f);
    unsigned r = u + 0x7FFFu + ((u >> 16) & 1u);   // round-to-nearest-even
    return (unsigned short)(r >> 16);
}
static __device__ __forceinline__ float bf2f(unsigned short b) {
    return __uint_as_float(((unsigned)b) << 16);
}
static __device__ __forceinline__ unsigned umin2(unsigned a, unsigned b) { return a < b ? a : b; }
static __device__ __forceinline__ unsigned umax2(unsigned a, unsigned b) { return a > b ? a : b; }

// fragment-ready layout: entity panel p=e>>5, k-slot q=k>>3:
//   u16 index = p*2048 + q*256 + (e&31)*8 + (k&7)
static __device__ __forceinline__ size_t fragidx(int e, int k) {
    return (size_t)(e >> 5) * 2048 + (size_t)(k >> 3) * 256 + (e & 31) * 8 + (k & 7);
}

// ---------------------------------------------------------------------------
// bitpack: stream the 1.07 GB mask SEQUENTIALLY (each wave owns a contiguous
// 128 KB range) -> 32 MB bit matrix bits[row][K/32]. training==0 -> all ones.
// 4 segments per iteration keeps 4 coalesced 256B loads in flight.
// ---------------------------------------------------------------------------
__global__ __launch_bounds__(256) void k_bitpack(const int* __restrict__ mask,
                                                 const int* __restrict__ training,
                                                 unsigned* __restrict__ bits,
                                                 long long nseg) {
    const int lane = threadIdx.x & 63;
    const long long wid = (long long)blockIdx.x * 4 + (threadIdx.x >> 6);
    const long long nw = (long long)gridDim.x * 4;
    const int tr = training[0];
    const long long spw = nseg / nw;             // segments per wave (contig)
    const long long s0 = wid * spw;
    for (long long j = 0; j < spw; j += 4) {
        const long long s = s0 + j;
        const int v0 = mask[(s + 0) * 64 + lane];
        const int v1 = mask[(s + 1) * 64 + lane];
        const int v2 = mask[(s + 2) * 64 + lane];
        const int v3 = mask[(s + 3) * 64 + lane];
        const unsigned long long b0 = __ballot(v0 != 0 || tr == 0);
        const unsigned long long b1 = __ballot(v1 != 0 || tr == 0);
        const unsigned long long b2 = __ballot(v2 != 0 || tr == 0);
        const unsigned long long b3 = __ballot(v3 != 0 || tr == 0);
        if (lane == 0) {
            unsigned long long* dst = (unsigned long long*)(bits + s * 2);
            dst[0] = b0; dst[1] = b1; dst[2] = b2; dst[3] = b3;   // 32B seq
        }
    }
}

// ---------------------------------------------------------------------------
// prep: normalize codebook. cb fp32 (for gather) + double-normalized hi/lo
// bf16 fragments.
// ---------------------------------------------------------------------------
__global__ __launch_bounds__(256) void k_prep_cb(const float* __restrict__ cbin,
                                                 float* __restrict__ cb,
                                                 unsigned short* __restrict__ ch,
                                                 unsigned short* __restrict__ cl) {
    const int t = threadIdx.x;
    const int wv = t >> 6, lane = t & 63;
    const int code = blockIdx.x * 4 + wv;
    float v = cbin[(size_t)code * D + lane];
    float ss = v * v;
    #pragma unroll
    for (int off = 32; off; off >>= 1) ss += __shfl_xor(ss, off, 64);
    const float c1 = v / (sqrtf(ss) + EPSV);
    cb[(size_t)code * D + lane] = c1;
    float ss2 = c1 * c1;
    #pragma unroll
    for (int off = 32; off; off >>= 1) ss2 += __shfl_xor(ss2, off, 64);
    const float c2 = c1 / (sqrtf(ss2) + EPSV);
    const unsigned short h = f2bf(c2);
    const size_t fi = fragidx(code, lane);
    ch[fi] = h;
    cl[fi] = f2bf(c2 - bf2f(h));
}

// ---------------------------------------------------------------------------
// prep: normalize x -> xn (fp32, straight to d_out region 2) + hi/lo fragments
// also zeroes fixcnt (stream-ordered before k_reduce2)
// ---------------------------------------------------------------------------
__global__ __launch_bounds__(256) void k_prep_x(const float* __restrict__ xin,
                                                float* __restrict__ xn,
                                                unsigned short* __restrict__ xh,
                                                unsigned short* __restrict__ xl,
                                                int* __restrict__ fixcnt) {
    const int t = threadIdx.x;
    if (blockIdx.x == 0 && t == 0) *fixcnt = 0;
    const int wv = t >> 6, lane = t & 63;
    const int row = blockIdx.x * 4 + wv;
    float v = xin[(size_t)row * D + lane];
    float ss = v * v;
    #pragma unroll
    for (int off = 32; off; off >>= 1) ss += __shfl_xor(ss, off, 64);
    const float xv = v / (sqrtf(ss) + EPSV);
    xn[(size_t)row * D + lane] = xv;
    const unsigned short h = f2bf(xv);
    const size_t fi = fragidx(row, lane);
    xh[fi] = h;
    xl[fi] = f2bf(xv - bf2f(h));
}

// ---------------------------------------------------------------------------
// main: 128 rows x 2048 codes per block (32 tiles of 64 codes), 4 waves.
// Swapped MFMA (A=codes, B=x-rows): acc col = x-row -> lane-local argmin.
// Mask comes from the bit matrix: 2 words/lane/tile, prefetched 1 tile
// ahead into registers. NO LDS, NO barriers, no staging. ks = bid&7 gives
// each XCD its own L2-resident ch/cl slice.
// ---------------------------------------------------------------------------
__global__ __launch_bounds__(256, 4) void k_mfma(const unsigned short* __restrict__ xh,
                                                 const unsigned short* __restrict__ xl,
                                                 const unsigned short* __restrict__ ch,
                                                 const unsigned short* __restrict__ cl,
                                                 const unsigned* __restrict__ bits,
                                                 const int* __restrict__ training,
                                                 unsigned* __restrict__ pk1,
                                                 unsigned* __restrict__ pk2,
                                                 int B, int K) {
    const int t = threadIdx.x;
    const int wv = t >> 6, lane = t & 63;
    const int lh = lane >> 5, lm = lane & 31;
    const int ks = (int)(blockIdx.x & 7);
    const int rb = (int)(blockIdx.x >> 3);
    const int tr = training[0];

    const short8* xh8 = (const short8*)xh;
    const short8* xl8 = (const short8*)xl;
    const short8* ch8 = (const short8*)ch;
    const short8* cl8 = (const short8*)cl;

    const int rp = rb * 4 + wv;                  // this wave's 32-row panel
    const int row = rp * 32 + lm;                // this lane's x-row
    const int lh4 = lh * 4;

    // B fragments (x rows), held for the whole block
    short8 bh[4], bl[4];
    #pragma unroll
    for (int s = 0; s < 4; ++s) {
        const size_t bi = (size_t)rp * 256 + (s * 2 + lh) * 32 + lm;
        bh[s] = xh8[bi];
        bl[s] = xl8[bi];
    }

    const unsigned* brow = bits + (size_t)row * (K >> 5) + ks * 64;

    unsigned k1 = 0xFFFFFFFFu, k2 = 0xFFFFFFFFu;
    unsigned cw0 = brow[0], cw1 = brow[1];       // current tile's bit words
    unsigned nw0, nw1;

    #pragma unroll 1
    for (int tt = 0; tt < 32; ++tt) {
        if (tt < 31) {                           // prefetch next tile's words
            nw0 = brow[(tt + 1) * 2];
            nw1 = brow[(tt + 1) * 2 + 1];
        }
        const int ct = ks * 32 + tt;             // global 64-code tile id
        #pragma unroll
        for (int p = 0; p < 2; ++p) {
            const int cp = ct * 2 + p;           // code panel of 32
            short8 ah[4], al[4];
            #pragma unroll
            for (int s = 0; s < 4; ++s) {
                const size_t ai = (size_t)cp * 256 + (s * 2 + lh) * 32 + lm;
                ah[s] = ch8[ai];
                al[s] = cl8[ai];
            }
            f32x16 acc;
            #pragma unroll
            for (int i = 0; i < 16; ++i) acc[i] = 0.f;
            #pragma unroll
            for (int s = 0; s < 4; ++s) {
                acc = __builtin_amdgcn_mfma_f32_32x32x16_bf16(ah[s], bh[s], acc, 0, 0, 0);
                acc = __builtin_amdgcn_mfma_f32_32x32x16_bf16(ah[s], bl[s], acc, 0, 0, 0);
                acc = __builtin_amdgcn_mfma_f32_32x32x16_bf16(al[s], bh[s], acc, 0, 0, 0);
            }
            // bit 'base' of nm2 == NOT kept(code kbase+base)
            const unsigned wp = p ? cw1 : cw0;
            const unsigned nm2 = tr ? ((~wp) >> lh4) : 0u;
            const unsigned kbase = (unsigned)(ct * 64 + p * 32 + lh4);
            #pragma unroll
            for (int r = 0; r < 16; ++r) {
                const int base = (r & 3) + 8 * (r >> 2);              // static
                const float qf = fmaf(acc[r], -65536.0f, 131072.0f);
                int qi = (int)qf;
                qi = qi < 0 ? 0 : (qi > 262143 ? 262143 : qi);
                unsigned key = ((unsigned)qi << 14) | kbase | (unsigned)base;
                key |= (unsigned)((int)(nm2 << (31 - base)) >> 31);   // dropped
                k2 = umin2(k2, umax2(k1, key));
                k1 = umin2(k1, key);
            }
        }
        cw0 = nw0; cw1 = nw1;
    }

    // merge the two half-lanes holding the same x-row
    const unsigned o1 = (unsigned)__shfl_xor((int)k1, 32, 64);
    const unsigned o2 = (unsigned)__shfl_xor((int)k2, 32, 64);
    const unsigned mx = umax2(k1, o1);
    k1 = umin2(k1, o1);
    k2 = umin2(umin2(k2, o2), mx);

    if (lh == 0) {                               // coalesced 32-dword writes
        pk1[(size_t)ks * B + row] = k1;
        pk2[(size_t)ks * B + row] = k2;
    }
}

// ---------------------------------------------------------------------------
// combine the 8 ksplit partials per row; flag rows with top-2 gap < 10 quanta
// ---------------------------------------------------------------------------
__global__ __launch_bounds__(256) void k_reduce2(const unsigned* __restrict__ pk1,
                                                 const unsigned* __restrict__ pk2,
                                                 int* __restrict__ bestidx,
                                                 int* __restrict__ fixlist,
                                                 int* __restrict__ fixcnt,
                                                 int B) {
    const int row = blockIdx.x * 256 + threadIdx.x;
    unsigned k1 = 0xFFFFFFFFu, k2 = 0xFFFFFFFFu;
    #pragma unroll
    for (int c = 0; c < 8; ++c) {
        const unsigned a1 = pk1[(size_t)c * B + row];
        const unsigned a2 = pk2[(size_t)c * B + row];
        k2 = umin2(umin2(k2, a2), umax2(k1, a1));
        k1 = umin2(k1, a1);
    }
    bestidx[row] = (int)(k1 & 16383u);
    if ((k2 >> 14) - (k1 >> 14) < 10u) {
        const int p = atomicAdd(fixcnt, 1);
        fixlist[p] = row;
    }
}

// ---------------------------------------------------------------------------
// gather + write all outputs
// ---------------------------------------------------------------------------
__global__ __launch_bounds__(256) void k_out(const float* __restrict__ xn,
                                             const float* __restrict__ cb,
                                             const int* __restrict__ bestidx,
                                             float* __restrict__ out, int B) {
    const int t = threadIdx.x;
    const int wv = t >> 6, lane = t & 63;
    const int row = blockIdx.x * 4 + wv;
    const int bi = bestidx[row];
    const float zv  = cb[(size_t)bi * D + lane];
    const float xnv = xn[(size_t)row * D + lane];
    out[(size_t)row * D + lane] = xnv + (zv - xnv);                 // z_q
    out[(size_t)B * D + (size_t)row * D + lane] = zv;               // z
    if (lane == 0) out[(size_t)3 * B * D + row] = (float)bi;        // index
}

// ---------------------------------------------------------------------------
// exact fp32 rescan for flagged (near-tie) rows; overwrites their outputs
// ---------------------------------------------------------------------------
__global__ __launch_bounds__(256) void k_fix(const float* __restrict__ xn,
                                             const float* __restrict__ cb,
                                             const int* __restrict__ mask,
                                             const int* __restrict__ training,
                                             const int* __restrict__ fixlist,
                                             const int* __restrict__ fixcnt,
                                             float* __restrict__ out, int B, int K) {
    const int nf = *fixcnt;
    const int tr = training[0];
    __shared__ float sv[256];
    __shared__ int   si[256];
    const int t = threadIdx.x;
    for (int i = blockIdx.x; i < nf; i += gridDim.x) {
        const int row = fixlist[i];
        const float* xr = xn + (size_t)row * D;
        float b1 = FLT_MAX; int i1 = 0;
        for (int k = t; k < K; k += 256) {
            const float* cr = cb + (size_t)k * D;
            float s = 0.f;
            #pragma unroll
            for (int d = 0; d < D; ++d) s = fmaf(xr[d], cr[d], s);
            const int m = mask[(size_t)row * K + k];
            const float dist = (tr && m == 0) ? 1000000000.0f : -s;
            if (dist < b1) { b1 = dist; i1 = k; }
        }
        sv[t] = b1; si[t] = i1;
        __syncthreads();
        for (int s = 128; s; s >>= 1) {
            if (t < s) {
                const float ov = sv[t + s]; const int oi = si[t + s];
                if (ov < sv[t] || (ov == sv[t] && oi < si[t])) { sv[t] = ov; si[t] = oi; }
            }
            __syncthreads();
        }
        const int bi = si[0];
        if (t < 64) {
            const float zv  = cb[(size_t)bi * D + t];
            const float xnv = xr[t];
            out[(size_t)row * D + t] = xnv + (zv - xnv);
            out[(size_t)B * D + (size_t)row * D + t] = zv;
        }
        if (t == 0) out[(size_t)3 * B * D + row] = (float)bi;
        __syncthreads();
    }
}

extern "C" void kernel_launch(void* const* d_in, const int* in_sizes, int n_in,
                              void* d_out, int out_size, void* d_ws, size_t ws_size,
                              hipStream_t stream) {
    const float* x    = (const float*)d_in[0];
    const float* cbin = (const float*)d_in[1];
    const int* mask   = (const int*)d_in[2];
    const int* train  = (const int*)d_in[3];
    const int B = in_sizes[0] / D;   // 16384
    const int K = in_sizes[1] / D;   // 16384
    float* out = (float*)d_out;
    float* out_xn = out + (size_t)2 * B * D;

    char* w = (char*)d_ws;
    float* cbw          = (float*)w;                               // 4 MB
    unsigned short* xhw = (unsigned short*)(w + (size_t)K * D * 4);
    unsigned short* xlw = xhw + (size_t)B * D;
    unsigned short* chw = xlw + (size_t)B * D;
    unsigned short* clw = chw + (size_t)K * D;
    unsigned* pk1       = (unsigned*)(clw + (size_t)K * D);        // B*8 u32
    unsigned* pk2       = pk1 + (size_t)B * 8;                     // B*8 u32
    int* bestidx        = (int*)(pk2 + (size_t)B * 8);
    int* fixlist        = bestidx + B;
    int* fixcnt         = fixlist + B;
    unsigned* bits      = (unsigned*)(fixcnt + 64);                // 32 MB

    const long long nseg = (long long)B * K / 64;
    k_bitpack<<<2048, 256, 0, stream>>>(mask, train, bits, nseg);
    k_prep_cb<<<K / 4, 256, 0, stream>>>(cbin, cbw, chw, clw);
    k_prep_x <<<B / 4, 256, 0, stream>>>(x, out_xn, xhw, xlw, fixcnt);
    k_mfma   <<<(B / 128) * 8, 256, 0, stream>>>(xhw, xlw, chw, clw, bits, train,
                                                 pk1, pk2, B, K);
    k_reduce2<<<B / 256, 256, 0, stream>>>(pk1, pk2, bestidx, fixlist, fixcnt, B);
    k_out    <<<B / 4, 256, 0, stream>>>(out_xn, cbw, bestidx, out, B);
    k_fix    <<<256, 256, 0, stream>>>(out_xn, cbw, mask, train, fixlist, fixcnt,
                                       out, B, K);
}

// Round 14
// 404.364 us; speedup vs baseline: 1.4127x; 1.3114x over previous
//
#include <hip/hip_runtime.h>
#include <math.h>
#include <float.h>

#define EPSV 1e-8f
constexpr int D = 64;

typedef __attribute__((ext_vector_type(8)))  short short8;
typedef __attribute__((ext_vector_type(16))) float f32x16;

static __device__ __forceinline__ unsigned short f2bf(float f) {
    unsigned u = __float_as_uint(f);
    unsigned r = u + 0x7FFFu + ((u >> 16) & 1u);   // round-to-nearest-even
    return (unsigned short)(r >> 16);
}
static __device__ __forceinline__ float bf2f(unsigned short b) {
    return __uint_as_float(((unsigned)b) << 16);
}
static __device__ __forceinline__ unsigned umin2(unsigned a, unsigned b) { return a < b ? a : b; }
static __device__ __forceinline__ unsigned umax2(unsigned a, unsigned b) { return a > b ? a : b; }

// fragment-ready layout: entity panel p=e>>5, k-slot q=k>>3:
//   u16 index = p*2048 + q*256 + (e&31)*8 + (k&7)
static __device__ __forceinline__ size_t fragidx(int e, int k) {
    return (size_t)(e >> 5) * 2048 + (size_t)(k >> 3) * 256 + (e & 31) * 8 + (k & 7);
}

// ---------------------------------------------------------------------------
// prep: normalize codebook. cb fp32 (for gather) + double-normalized hi/lo
// bf16 fragments.
// ---------------------------------------------------------------------------
__global__ __launch_bounds__(256) void k_prep_cb(const float* __restrict__ cbin,
                                                 float* __restrict__ cb,
                                                 unsigned short* __restrict__ ch,
                                                 unsigned short* __restrict__ cl) {
    const int t = threadIdx.x;
    const int wv = t >> 6, lane = t & 63;
    const int code = blockIdx.x * 4 + wv;
    float v = cbin[(size_t)code * D + lane];
    float ss = v * v;
    #pragma unroll
    for (int off = 32; off; off >>= 1) ss += __shfl_xor(ss, off, 64);
    const float c1 = v / (sqrtf(ss) + EPSV);
    cb[(size_t)code * D + lane] = c1;
    float ss2 = c1 * c1;
    #pragma unroll
    for (int off = 32; off; off >>= 1) ss2 += __shfl_xor(ss2, off, 64);
    const float c2 = c1 / (sqrtf(ss2) + EPSV);
    const unsigned short h = f2bf(c2);
    const size_t fi = fragidx(code, lane);
    ch[fi] = h;
    cl[fi] = f2bf(c2 - bf2f(h));
}

// ---------------------------------------------------------------------------
// prep: normalize x -> xn (fp32, straight to d_out region 2) + hi/lo fragments
// also zeroes fixcnt (stream-ordered before k_reduce2)
// ---------------------------------------------------------------------------
__global__ __launch_bounds__(256) void k_prep_x(const float* __restrict__ xin,
                                                float* __restrict__ xn,
                                                unsigned short* __restrict__ xh,
                                                unsigned short* __restrict__ xl,
                                                int* __restrict__ fixcnt) {
    const int t = threadIdx.x;
    if (blockIdx.x == 0 && t == 0) *fixcnt = 0;
    const int wv = t >> 6, lane = t & 63;
    const int row = blockIdx.x * 4 + wv;
    float v = xin[(size_t)row * D + lane];
    float ss = v * v;
    #pragma unroll
    for (int off = 32; off; off >>= 1) ss += __shfl_xor(ss, off, 64);
    const float xv = v / (sqrtf(ss) + EPSV);
    xn[(size_t)row * D + lane] = xv;
    const unsigned short h = f2bf(xv);
    const size_t fi = fragidx(row, lane);
    xh[fi] = h;
    xl[fi] = f2bf(xv - bf2f(h));
}

// ---------------------------------------------------------------------------
// main: 128 rows x 2048 codes per block (32 tiles of 64 codes), 4 waves.
// Swapped MFMA (A=codes, B=x-rows): acc col = x-row -> lane-local argmin.
// Mask: per-wave PRIVATE LDS slices staged via global_load_lds, double
// buffered. NO __syncthreads: tile sync is per-wave s_waitcnt vmcnt(8)
// (8 = the just-issued next-tile stage ops; everything older is complete)
// + sched_barrier(0). Waves drift freely -> HBM stays continuously fed.
// ---------------------------------------------------------------------------
__global__ __launch_bounds__(256, 2) void k_mfma(const unsigned short* __restrict__ xh,
                                                 const unsigned short* __restrict__ xl,
                                                 const unsigned short* __restrict__ ch,
                                                 const unsigned short* __restrict__ cl,
                                                 const int* __restrict__ mask,
                                                 const int* __restrict__ training,
                                                 unsigned* __restrict__ pk1,
                                                 unsigned* __restrict__ pk2,
                                                 int B, int K) {
    __shared__ int msk[2][4][32][64];            // 64 KB: [buf][wave][row][code]
    const int t = threadIdx.x;
    const int wv = t >> 6, lane = t & 63;
    const int lh = lane >> 5, lm = lane & 31;
    const int ks = (int)(blockIdx.x & 7);
    const int rb = (int)(blockIdx.x >> 3);
    const int tr = training[0];

    const short8* xh8 = (const short8*)xh;
    const short8* xl8 = (const short8*)xl;
    const short8* ch8 = (const short8*)ch;
    const short8* cl8 = (const short8*)cl;

    const int rp = rb * 4 + wv;                  // this wave's 32-row panel
    const int row = rp * 32 + lm;                // this lane's x-row
    const int lh4 = lh * 4;
    const int lsub = lane >> 4;                  // 0..3 (row within gll group)
    const int lquad = lane & 15;                 // 16B slot within row

    // B fragments (x rows), held for the whole block
    short8 bh[4], bl[4];
    #pragma unroll
    for (int s = 0; s < 4; ++s) {
        const size_t bi = (size_t)rp * 256 + (s * 2 + lh) * 32 + lm;
        bh[s] = xh8[bi];
        bl[s] = xl8[bi];
    }

    const int* mbase = mask + (size_t)(rp * 32) * K + ks * (K / 8);

    unsigned k1 = 0xFFFFFFFFu, k2 = 0xFFFFFFFFu;

    // stage tile tt_ into buffer b_: 8 x global_load_lds dwordx4 per wave.
    // source quad pre-swizzled (quad ^ (row&15)); reads undo with same XOR.
#define STAGE(b_, tt_) do {                                                    \
    _Pragma("unroll")                                                          \
    for (int j = 0; j < 8; ++j) {                                              \
        const int rj = j * 4 + lsub;                                           \
        const int qz = lquad ^ (rj & 15);                                      \
        const int* src = mbase + (size_t)rj * K + (tt_) * 64 + qz * 4;         \
        __builtin_amdgcn_global_load_lds(                                      \
            (const __attribute__((address_space(1))) void*)src,                \
            (__attribute__((address_space(3))) void*)(&msk[b_][wv][j * 4][0]), \
            16, 0, 0);                                                         \
    }                                                                          \
} while (0)

    STAGE(0, 0);

    #pragma unroll 1
    for (int tt = 0; tt < 32; ++tt) {
        if (tt < 31) {
            STAGE((tt + 1) & 1, tt + 1);
            // 8 newest ops are stage(tt+1); <=8 outstanding => stage(tt) done
            asm volatile("s_waitcnt vmcnt(8)" ::: "memory");
        } else {
            asm volatile("s_waitcnt vmcnt(0)" ::: "memory");
        }
        __builtin_amdgcn_sched_barrier(0);
        const int bsel = tt & 1;

        // build this lane's kept-bit word for its 32 codes of this tile
        unsigned kept = 0;
        #pragma unroll
        for (int i = 0; i < 8; ++i) {
            const int q = lh + 2 * i;            // quad of codes this lane uses
            const int4 v = *(const int4*)&msk[bsel][wv][lm][(q ^ (lm & 15)) * 4];
            kept |= (v.x != 0 ? 1u : 0u) << (i * 4 + 0);
            kept |= (v.y != 0 ? 1u : 0u) << (i * 4 + 1);
            kept |= (v.z != 0 ? 1u : 0u) << (i * 4 + 2);
            kept |= (v.w != 0 ? 1u : 0u) << (i * 4 + 3);
        }
        const unsigned nm = tr ? ~kept : 0u;     // bit=1 -> dropped code

        const int ct = ks * 32 + tt;             // global 64-code tile id
        #pragma unroll
        for (int p = 0; p < 2; ++p) {
            const int cp = ct * 2 + p;           // code panel of 32
            short8 ah[4], al[4];
            #pragma unroll
            for (int s = 0; s < 4; ++s) {
                const size_t ai = (size_t)cp * 256 + (s * 2 + lh) * 32 + lm;
                ah[s] = ch8[ai];
                al[s] = cl8[ai];
            }
            f32x16 acc;
            #pragma unroll
            for (int i = 0; i < 16; ++i) acc[i] = 0.f;
            #pragma unroll
            for (int s = 0; s < 4; ++s) {
                acc = __builtin_amdgcn_mfma_f32_32x32x16_bf16(ah[s], bh[s], acc, 0, 0, 0);
                acc = __builtin_amdgcn_mfma_f32_32x32x16_bf16(ah[s], bl[s], acc, 0, 0, 0);
                acc = __builtin_amdgcn_mfma_f32_32x32x16_bf16(al[s], bh[s], acc, 0, 0, 0);
            }
            const unsigned kbase = (unsigned)(ct * 64 + p * 32 + lh4);
            #pragma unroll
            for (int r = 0; r < 16; ++r) {
                const int base = (r & 3) + 8 * (r >> 2);              // static
                const int bitpos = p * 16 + (r >> 2) * 4 + (r & 3);   // static
                const float qf = fmaf(acc[r], -65536.0f, 131072.0f);
                int qi = (int)qf;
                qi = qi < 0 ? 0 : (qi > 262143 ? 262143 : qi);
                unsigned key = ((unsigned)qi << 14) | kbase | (unsigned)base;
                key |= (unsigned)((int)(nm << (31 - bitpos)) >> 31);  // dropped
                k2 = umin2(k2, umax2(k1, key));
                k1 = umin2(k1, key);
            }
        }
    }
#undef STAGE

    // merge the two half-lanes holding the same x-row
    const unsigned o1 = (unsigned)__shfl_xor((int)k1, 32, 64);
    const unsigned o2 = (unsigned)__shfl_xor((int)k2, 32, 64);
    const unsigned mx = umax2(k1, o1);
    k1 = umin2(k1, o1);
    k2 = umin2(umin2(k2, o2), mx);

    if (lh == 0) {                               // coalesced 32-dword writes
        pk1[(size_t)ks * B + row] = k1;
        pk2[(size_t)ks * B + row] = k2;
    }
}

// ---------------------------------------------------------------------------
// combine the 8 ksplit partials per row; flag rows with top-2 gap < 10 quanta
// ---------------------------------------------------------------------------
__global__ __launch_bounds__(256) void k_reduce2(const unsigned* __restrict__ pk1,
                                                 const unsigned* __restrict__ pk2,
                                                 int* __restrict__ bestidx,
                                                 int* __restrict__ fixlist,
                                                 int* __restrict__ fixcnt,
                                                 int B) {
    const int row = blockIdx.x * 256 + threadIdx.x;
    unsigned k1 = 0xFFFFFFFFu, k2 = 0xFFFFFFFFu;
    #pragma unroll
    for (int c = 0; c < 8; ++c) {
        const unsigned a1 = pk1[(size_t)c * B + row];
        const unsigned a2 = pk2[(size_t)c * B + row];
        k2 = umin2(umin2(k2, a2), umax2(k1, a1));
        k1 = umin2(k1, a1);
    }
    bestidx[row] = (int)(k1 & 16383u);
    if ((k2 >> 14) - (k1 >> 14) < 10u) {
        const int p = atomicAdd(fixcnt, 1);
        fixlist[p] = row;
    }
}

// ---------------------------------------------------------------------------
// gather + write all outputs
// ---------------------------------------------------------------------------
__global__ __launch_bounds__(256) void k_out(const float* __restrict__ xn,
                                             const float* __restrict__ cb,
                                             const int* __restrict__ bestidx,
                                             float* __restrict__ out, int B) {
    const int t = threadIdx.x;
    const int wv = t >> 6, lane = t & 63;
    const int row = blockIdx.x * 4 + wv;
    const int bi = bestidx[row];
    const float zv  = cb[(size_t)bi * D + lane];
    const float xnv = xn[(size_t)row * D + lane];
    out[(size_t)row * D + lane] = xnv + (zv - xnv);                 // z_q
    out[(size_t)B * D + (size_t)row * D + lane] = zv;               // z
    if (lane == 0) out[(size_t)3 * B * D + row] = (float)bi;        // index
}

// ---------------------------------------------------------------------------
// exact fp32 rescan for flagged (near-tie) rows; overwrites their outputs
// ---------------------------------------------------------------------------
__global__ __launch_bounds__(256) void k_fix(const float* __restrict__ xn,
                                             const float* __restrict__ cb,
                                             const int* __restrict__ mask,
                                             const int* __restrict__ training,
                                             const int* __restrict__ fixlist,
                                             const int* __restrict__ fixcnt,
                                             float* __restrict__ out, int B, int K) {
    const int nf = *fixcnt;
    const int tr = training[0];
    __shared__ float sv[256];
    __shared__ int   si[256];
    const int t = threadIdx.x;
    for (int i = blockIdx.x; i < nf; i += gridDim.x) {
        const int row = fixlist[i];
        const float* xr = xn + (size_t)row * D;
        float b1 = FLT_MAX; int i1 = 0;
        for (int k = t; k < K; k += 256) {
            const float* cr = cb + (size_t)k * D;
            float s = 0.f;
            #pragma unroll
            for (int d = 0; d < D; ++d) s = fmaf(xr[d], cr[d], s);
            const int m = mask[(size_t)row * K + k];
            const float dist = (tr && m == 0) ? 1000000000.0f : -s;
            if (dist < b1) { b1 = dist; i1 = k; }
        }
        sv[t] = b1; si[t] = i1;
        __syncthreads();
        for (int s = 128; s; s >>= 1) {
            if (t < s) {
                const float ov = sv[t + s]; const int oi = si[t + s];
                if (ov < sv[t] || (ov == sv[t] && oi < si[t])) { sv[t] = ov; si[t] = oi; }
            }
            __syncthreads();
        }
        const int bi = si[0];
        if (t < 64) {
            const float zv  = cb[(size_t)bi * D + t];
            const float xnv = xr[t];
            out[(size_t)row * D + t] = xnv + (zv - xnv);
            out[(size_t)B * D + (size_t)row * D + t] = zv;
        }
        if (t == 0) out[(size_t)3 * B * D + row] = (float)bi;
        __syncthreads();
    }
}

extern "C" void kernel_launch(void* const* d_in, const int* in_sizes, int n_in,
                              void* d_out, int out_size, void* d_ws, size_t ws_size,
                              hipStream_t stream) {
    const float* x    = (const float*)d_in[0];
    const float* cbin = (const float*)d_in[1];
    const int* mask   = (const int*)d_in[2];
    const int* train  = (const int*)d_in[3];
    const int B = in_sizes[0] / D;   // 16384
    const int K = in_sizes[1] / D;   // 16384
    float* out = (float*)d_out;
    float* out_xn = out + (size_t)2 * B * D;

    char* w = (char*)d_ws;
    float* cbw          = (float*)w;                               // 4 MB
    unsigned short* xhw = (unsigned short*)(w + (size_t)K * D * 4);
    unsigned short* xlw = xhw + (size_t)B * D;
    unsigned short* chw = xlw + (size_t)B * D;
    unsigned short* clw = chw + (size_t)K * D;
    unsigned* pk1       = (unsigned*)(clw + (size_t)K * D);        // B*8 u32
    unsigned* pk2       = pk1 + (size_t)B * 8;                     // B*8 u32
    int* bestidx        = (int*)(pk2 + (size_t)B * 8);
    int* fixlist        = bestidx + B;
    int* fixcnt         = fixlist + B;

    k_prep_cb<<<K / 4, 256, 0, stream>>>(cbin, cbw, chw, clw);
    k_prep_x <<<B / 4, 256, 0, stream>>>(x, out_xn, xhw, xlw, fixcnt);
    k_mfma   <<<(B / 128) * 8, 256, 0, stream>>>(xhw, xlw, chw, clw, mask, train,
                                                 pk1, pk2, B, K);
    k_reduce2<<<B / 256, 256, 0, stream>>>(pk1, pk2, bestidx, fixlist, fixcnt, B);
    k_out    <<<B / 4, 256, 0, stream>>>(out_xn, cbw, bestidx, out, B);
    k_fix    <<<256, 256, 0, stream>>>(out_xn, cbw, mask, train, fixlist, fixcnt,
                                       out, B, K);
}